// Round 1
// baseline (5217.809 us; speedup 1.0000x reference)
//
#include <hip/hip_runtime.h>

// LightGCN 3-layer propagation on MI355X.
// ego: [150000, 64] fp32. Per layer: new_ego[src[e]] += norm[e] * ego[dst[e]].
// acc = sum of ego over layers 0..3; out = acc / 4.

#define NUM_USERS 100000
#define NUM_ITEMS 50000
#define EMB_DIM   64
#define N_EDGES   2000000
#define N_NODES   (NUM_USERS + NUM_ITEMS)          // 150000
#define NODE_FLOATS (N_NODES * EMB_DIM)            // 9,600,000
#define NODE_F4     (NODE_FLOATS / 4)              // 2,400,000

// init: egoA = concat(user, item); acc(d_out) = same; egoB = 0
__global__ void lgcn_init(const float4* __restrict__ user,
                          const float4* __restrict__ item,
                          float4* __restrict__ egoA,
                          float4* __restrict__ egoB,
                          float4* __restrict__ acc) {
    const int n_user4 = NUM_USERS * EMB_DIM / 4;   // 1,600,000
    for (int i = blockIdx.x * blockDim.x + threadIdx.x; i < NODE_F4;
         i += gridDim.x * blockDim.x) {
        float4 v = (i < n_user4) ? user[i] : item[i - n_user4];
        egoA[i] = v;
        acc[i]  = v;
        egoB[i] = make_float4(0.f, 0.f, 0.f, 0.f);
    }
}

// scatter: 16 threads per edge, 4 dims each (float4 gather + 4 fp32 atomics)
__global__ void lgcn_scatter(const float* __restrict__ ego,
                             float* __restrict__ nego,
                             const int* __restrict__ src,
                             const int* __restrict__ dst,
                             const float* __restrict__ norm) {
    int idx = blockIdx.x * blockDim.x + threadIdx.x;   // 32M threads total
    int e = idx >> 4;
    if (e >= N_EDGES) return;
    int q = (idx & 15) << 2;                            // dim offset 0..60
    int s = src[e];
    int d = dst[e];
    float w = norm[e];
    const float4 v = *(const float4*)(ego + d * EMB_DIM + q);
    float* p = nego + s * EMB_DIM + q;
    unsafeAtomicAdd(p + 0, w * v.x);
    unsafeAtomicAdd(p + 1, w * v.y);
    unsafeAtomicAdd(p + 2, w * v.z);
    unsafeAtomicAdd(p + 3, w * v.w);
}

// acc = (acc + nego) * scale ; other = 0 (preps next layer's destination)
__global__ void lgcn_acc(const float4* __restrict__ nego,
                         float4* __restrict__ other,
                         float4* __restrict__ acc,
                         float scale) {
    for (int i = blockIdx.x * blockDim.x + threadIdx.x; i < NODE_F4;
         i += gridDim.x * blockDim.x) {
        float4 a = acc[i];
        float4 b = nego[i];
        a.x = (a.x + b.x) * scale;
        a.y = (a.y + b.y) * scale;
        a.z = (a.z + b.z) * scale;
        a.w = (a.w + b.w) * scale;
        acc[i] = a;
        other[i] = make_float4(0.f, 0.f, 0.f, 0.f);
    }
}

extern "C" void kernel_launch(void* const* d_in, const int* in_sizes, int n_in,
                              void* d_out, int out_size, void* d_ws, size_t ws_size,
                              hipStream_t stream) {
    const float* user_emb  = (const float*)d_in[0];
    const float* item_emb  = (const float*)d_in[1];
    const float* edge_norm = (const float*)d_in[2];
    const int*   edge_src  = (const int*)d_in[3];
    const int*   edge_dst  = (const int*)d_in[4];
    float* acc  = (float*)d_out;                       // 150000*64 floats
    float* egoA = (float*)d_ws;                        // 38.4 MB
    float* egoB = egoA + NODE_FLOATS;                  // 38.4 MB

    const int EW_BLOCKS = 4096, EW_THREADS = 256;
    const int SC_THREADS = 256;
    const int SC_BLOCKS = (N_EDGES * 16) / SC_THREADS; // 125000, exact

    lgcn_init<<<EW_BLOCKS, EW_THREADS, 0, stream>>>(
        (const float4*)user_emb, (const float4*)item_emb,
        (float4*)egoA, (float4*)egoB, (float4*)acc);

    // Layer 1: A -> B ; acc += B ; zero A
    lgcn_scatter<<<SC_BLOCKS, SC_THREADS, 0, stream>>>(egoA, egoB, edge_src, edge_dst, edge_norm);
    lgcn_acc<<<EW_BLOCKS, EW_THREADS, 0, stream>>>((const float4*)egoB, (float4*)egoA, (float4*)acc, 1.0f);

    // Layer 2: B -> A ; acc += A ; zero B
    lgcn_scatter<<<SC_BLOCKS, SC_THREADS, 0, stream>>>(egoB, egoA, edge_src, edge_dst, edge_norm);
    lgcn_acc<<<EW_BLOCKS, EW_THREADS, 0, stream>>>((const float4*)egoA, (float4*)egoB, (float4*)acc, 1.0f);

    // Layer 3: A -> B ; acc = (acc + B) * 0.25 ; (zeroing A harmless)
    lgcn_scatter<<<SC_BLOCKS, SC_THREADS, 0, stream>>>(egoA, egoB, edge_src, edge_dst, edge_norm);
    lgcn_acc<<<EW_BLOCKS, EW_THREADS, 0, stream>>>((const float4*)egoB, (float4*)egoA, (float4*)acc, 0.25f);
}

// Round 2
// 632.780 us; speedup vs baseline: 8.2458x; 8.2458x over previous
//
#include <hip/hip_runtime.h>

// LightGCN 3-layer propagation, pull-based (CSR) — no float atomics.
// Per layer: nego[n][d] = sum over in-edges(n) of norm * ego[dst][d]
// acc accumulates layers 0..3 in d_out; final scale 1/4.

#define NUM_USERS 100000
#define NUM_ITEMS 50000
#define EMB_DIM   64
#define N_EDGES   2000000
#define N_NODES   (NUM_USERS + NUM_ITEMS)          // 150000
#define NODE_FLOATS (N_NODES * EMB_DIM)            // 9,600,000
#define NODE_F4     (NODE_FLOATS / 4)              // 2,400,000
#define SCAN_BLK    256
#define NBLK        ((N_NODES + SCAN_BLK - 1) / SCAN_BLK)   // 586

// ---------- init: egoA = concat(user,item); acc = same ----------
__global__ void lgcn_init(const float4* __restrict__ user,
                          const float4* __restrict__ item,
                          float4* __restrict__ egoA,
                          float4* __restrict__ acc) {
    const int n_user4 = NUM_USERS * EMB_DIM / 4;
    for (int i = blockIdx.x * blockDim.x + threadIdx.x; i < NODE_F4;
         i += gridDim.x * blockDim.x) {
        float4 v = (i < n_user4) ? user[i] : item[i - n_user4];
        egoA[i] = v;
        acc[i]  = v;
    }
}

// ---------- CSR build ----------
__global__ void zero_ints(int* __restrict__ p, int n) {
    for (int i = blockIdx.x * blockDim.x + threadIdx.x; i < n;
         i += gridDim.x * blockDim.x)
        p[i] = 0;
}

__global__ void hist_src(const int* __restrict__ src, int* __restrict__ counts) {
    for (int e = blockIdx.x * blockDim.x + threadIdx.x; e < N_EDGES;
         e += gridDim.x * blockDim.x)
        atomicAdd(&counts[src[e]], 1);
}

// block-level exclusive scan of counts -> rowPtr (partial), block totals -> blkSum
__global__ void scan_blocks(const int* __restrict__ counts,
                            int* __restrict__ rowPtr,
                            int* __restrict__ blkSum) {
    __shared__ int s[SCAN_BLK];
    int t = threadIdx.x;
    int i = blockIdx.x * SCAN_BLK + t;
    int v = (i < N_NODES) ? counts[i] : 0;
    s[t] = v;
    __syncthreads();
    for (int off = 1; off < SCAN_BLK; off <<= 1) {
        int x = (t >= off) ? s[t - off] : 0;
        __syncthreads();
        s[t] += x;
        __syncthreads();
    }
    if (i < N_NODES) rowPtr[i] = s[t] - v;   // exclusive, pre-offset
    if (t == SCAN_BLK - 1) blkSum[blockIdx.x] = s[t];
}

// single-block exclusive scan over NBLK block sums (NBLK <= 1024)
__global__ void scan_tops(int* __restrict__ blkSum) {
    __shared__ int s[1024];
    int t = threadIdx.x;
    int v = (t < NBLK) ? blkSum[t] : 0;
    s[t] = v;
    __syncthreads();
    for (int off = 1; off < 1024; off <<= 1) {
        int x = (t >= off) ? s[t - off] : 0;
        __syncthreads();
        s[t] += x;
        __syncthreads();
    }
    if (t < NBLK) blkSum[t] = s[t] - v;      // exclusive
}

__global__ void add_offsets(int* __restrict__ rowPtr,
                            int* __restrict__ cursor,
                            const int* __restrict__ blkSum) {
    int i = blockIdx.x * SCAN_BLK + threadIdx.x;
    if (i < N_NODES) {
        int r = rowPtr[i] + blkSum[blockIdx.x];
        rowPtr[i] = r;
        cursor[i] = r;
    }
    if (i == 0) rowPtr[N_NODES] = N_EDGES;
}

// counting-sort fill: pairs[pos] = (dst, norm) bucketed by src
__global__ void fill_pairs(const int* __restrict__ src,
                           const int* __restrict__ dst,
                           const float* __restrict__ norm,
                           int* __restrict__ cursor,
                           int2* __restrict__ pairs) {
    for (int e = blockIdx.x * blockDim.x + threadIdx.x; e < N_EDGES;
         e += gridDim.x * blockDim.x) {
        int s = src[e];
        int pos = atomicAdd(&cursor[s], 1);
        pairs[pos] = make_int2(dst[e], __float_as_int(norm[e]));
    }
}

// ---------- gather: one wave per node, lane = dim ----------
__global__ void lgcn_gather(const float* __restrict__ ego,
                            float* __restrict__ nego,
                            float* __restrict__ acc,
                            const int* __restrict__ rowPtr,
                            const int2* __restrict__ pairs,
                            float scale, int writeEgo) {
    int node = blockIdx.x * 4 + (threadIdx.x >> 6);
    int lane = threadIdx.x & 63;
    if (node >= N_NODES) return;
    int beg = rowPtr[node];
    int end = rowPtr[node + 1];

    float s0 = 0.f, s1 = 0.f, s2 = 0.f, s3 = 0.f;
    int i = beg;
    for (; i + 4 <= end; i += 4) {
        int2 p0 = pairs[i + 0];
        int2 p1 = pairs[i + 1];
        int2 p2 = pairs[i + 2];
        int2 p3 = pairs[i + 3];
        s0 += __int_as_float(p0.y) * ego[(long)p0.x * EMB_DIM + lane];
        s1 += __int_as_float(p1.y) * ego[(long)p1.x * EMB_DIM + lane];
        s2 += __int_as_float(p2.y) * ego[(long)p2.x * EMB_DIM + lane];
        s3 += __int_as_float(p3.y) * ego[(long)p3.x * EMB_DIM + lane];
    }
    for (; i < end; ++i) {
        int2 p = pairs[i];
        s0 += __int_as_float(p.y) * ego[(long)p.x * EMB_DIM + lane];
    }
    float sum = (s0 + s1) + (s2 + s3);

    int oi = node * EMB_DIM + lane;
    acc[oi] = (acc[oi] + sum) * scale;
    if (writeEgo) nego[oi] = sum;
}

extern "C" void kernel_launch(void* const* d_in, const int* in_sizes, int n_in,
                              void* d_out, int out_size, void* d_ws, size_t ws_size,
                              hipStream_t stream) {
    const float* user_emb  = (const float*)d_in[0];
    const float* item_emb  = (const float*)d_in[1];
    const float* edge_norm = (const float*)d_in[2];
    const int*   edge_src  = (const int*)d_in[3];
    const int*   edge_dst  = (const int*)d_in[4];
    float* acc = (float*)d_out;

    // workspace layout (16B aligned)
    char* w = (char*)d_ws;
    float* egoA   = (float*)w;                          w += (size_t)NODE_FLOATS * 4;   // 38.4 MB
    float* egoB   = (float*)w;                          w += (size_t)NODE_FLOATS * 4;   // 38.4 MB
    int2*  pairs  = (int2*)w;                           w += (size_t)N_EDGES * 8;       // 16 MB
    int*   rowPtr = (int*)w;                            w += (size_t)(N_NODES + 4) * 4;
    int*   cursor = (int*)w;                            w += (size_t)N_NODES * 4;
    int*   counts = (int*)w;                            w += (size_t)N_NODES * 4;
    int*   blkSum = (int*)w;

    const int EW_BLOCKS = 2048, T = 256;
    const int EDGE_BLOCKS = 2048;
    const int GATHER_BLOCKS = (N_NODES + 3) / 4;        // 4 waves/block, 1 node/wave

    lgcn_init<<<EW_BLOCKS, T, 0, stream>>>(
        (const float4*)user_emb, (const float4*)item_emb,
        (float4*)egoA, (float4*)acc);

    // CSR build (once; reused by all 3 layers)
    zero_ints<<<(N_NODES + T - 1) / T, T, 0, stream>>>(counts, N_NODES);
    hist_src<<<EDGE_BLOCKS, T, 0, stream>>>(edge_src, counts);
    scan_blocks<<<NBLK, SCAN_BLK, 0, stream>>>(counts, rowPtr, blkSum);
    scan_tops<<<1, 1024, 0, stream>>>(blkSum);
    add_offsets<<<NBLK, SCAN_BLK, 0, stream>>>(rowPtr, cursor, blkSum);
    fill_pairs<<<EDGE_BLOCKS, T, 0, stream>>>(edge_src, edge_dst, edge_norm, cursor, pairs);

    // Layer 1: read A, write B, acc += B
    lgcn_gather<<<GATHER_BLOCKS, T, 0, stream>>>(egoA, egoB, acc, rowPtr, pairs, 1.0f, 1);
    // Layer 2: read B, write A, acc += A
    lgcn_gather<<<GATHER_BLOCKS, T, 0, stream>>>(egoB, egoA, acc, rowPtr, pairs, 1.0f, 1);
    // Layer 3: read A, acc = (acc + ego3) * 0.25, no ego write
    lgcn_gather<<<GATHER_BLOCKS, T, 0, stream>>>(egoA, egoB, acc, rowPtr, pairs, 0.25f, 0);
}

// Round 3
// 537.599 us; speedup vs baseline: 9.7058x; 1.1770x over previous
//
#include <hip/hip_runtime.h>

// LightGCN 3-layer propagation, pull-based CSR, bf16 ego intermediates.
// acc (d_out) stays fp32. Per layer: nego[n] = sum_{in-edges} norm * ego[dst].

#define NUM_USERS 100000
#define NUM_ITEMS 50000
#define EMB_DIM   64
#define N_EDGES   2000000
#define N_NODES   (NUM_USERS + NUM_ITEMS)          // 150000
#define NODE_FLOATS (N_NODES * EMB_DIM)            // 9,600,000
#define NODE_F4     (NODE_FLOATS / 4)              // 2,400,000
#define SCAN_BLK    256
#define NBLK        ((N_NODES + SCAN_BLK - 1) / SCAN_BLK)   // 586

typedef unsigned int uint;
typedef unsigned short ushort;

__device__ __forceinline__ uint pack2_bf16(float a, float b) {
    uint ua = __float_as_uint(a), ub = __float_as_uint(b);
    ua += 0x7FFFu + ((ua >> 16) & 1u);      // RNE
    ub += 0x7FFFu + ((ub >> 16) & 1u);
    return (ua >> 16) | (ub & 0xFFFF0000u);
}
__device__ __forceinline__ float bflo(uint u) { return __uint_as_float(u << 16); }
__device__ __forceinline__ float bfhi(uint u) { return __uint_as_float(u & 0xFFFF0000u); }

// ---------- init: egoA(bf16) = concat(user,item); acc(fp32) = same ----------
__global__ void lgcn_init(const float4* __restrict__ user,
                          const float4* __restrict__ item,
                          uint2* __restrict__ egoA,
                          float4* __restrict__ acc) {
    const int n_user4 = NUM_USERS * EMB_DIM / 4;
    for (int i = blockIdx.x * blockDim.x + threadIdx.x; i < NODE_F4;
         i += gridDim.x * blockDim.x) {
        float4 v = (i < n_user4) ? user[i] : item[i - n_user4];
        acc[i]  = v;
        egoA[i] = make_uint2(pack2_bf16(v.x, v.y), pack2_bf16(v.z, v.w));
    }
}

// ---------- CSR build ----------
__global__ void zero_ints(int* __restrict__ p, int n) {
    for (int i = blockIdx.x * blockDim.x + threadIdx.x; i < n;
         i += gridDim.x * blockDim.x)
        p[i] = 0;
}

__global__ void hist_src(const int* __restrict__ src, int* __restrict__ counts) {
    int base = (blockIdx.x * blockDim.x + threadIdx.x) * 4;
    if (base >= N_EDGES) return;
    int4 s = *(const int4*)(src + base);
    atomicAdd(&counts[s.x], 1);
    atomicAdd(&counts[s.y], 1);
    atomicAdd(&counts[s.z], 1);
    atomicAdd(&counts[s.w], 1);
}

__global__ void scan_blocks(const int* __restrict__ counts,
                            int* __restrict__ rowPtr,
                            int* __restrict__ blkSum) {
    __shared__ int s[SCAN_BLK];
    int t = threadIdx.x;
    int i = blockIdx.x * SCAN_BLK + t;
    int v = (i < N_NODES) ? counts[i] : 0;
    s[t] = v;
    __syncthreads();
    for (int off = 1; off < SCAN_BLK; off <<= 1) {
        int x = (t >= off) ? s[t - off] : 0;
        __syncthreads();
        s[t] += x;
        __syncthreads();
    }
    if (i < N_NODES) rowPtr[i] = s[t] - v;
    if (t == SCAN_BLK - 1) blkSum[blockIdx.x] = s[t];
}

__global__ void scan_tops(int* __restrict__ blkSum) {
    __shared__ int s[1024];
    int t = threadIdx.x;
    int v = (t < NBLK) ? blkSum[t] : 0;
    s[t] = v;
    __syncthreads();
    for (int off = 1; off < 1024; off <<= 1) {
        int x = (t >= off) ? s[t - off] : 0;
        __syncthreads();
        s[t] += x;
        __syncthreads();
    }
    if (t < NBLK) blkSum[t] = s[t] - v;
}

__global__ void add_offsets(int* __restrict__ rowPtr,
                            int* __restrict__ cursor,
                            const int* __restrict__ blkSum) {
    int i = blockIdx.x * SCAN_BLK + threadIdx.x;
    if (i < N_NODES) {
        int r = rowPtr[i] + blkSum[blockIdx.x];
        rowPtr[i] = r;
        cursor[i] = r;
    }
    if (i == 0) rowPtr[N_NODES] = N_EDGES;
}

// counting-sort fill, 4 edges/thread for atomic MLP
__global__ void fill_pairs(const int* __restrict__ src,
                           const int* __restrict__ dst,
                           const float* __restrict__ norm,
                           int* __restrict__ cursor,
                           int2* __restrict__ pairs) {
    int base = (blockIdx.x * blockDim.x + threadIdx.x) * 4;
    if (base >= N_EDGES) return;
    int4   s = *(const int4*)(src + base);
    int4   d = *(const int4*)(dst + base);
    float4 w = *(const float4*)(norm + base);
    int p0 = atomicAdd(&cursor[s.x], 1);
    int p1 = atomicAdd(&cursor[s.y], 1);
    int p2 = atomicAdd(&cursor[s.z], 1);
    int p3 = atomicAdd(&cursor[s.w], 1);
    pairs[p0] = make_int2(d.x, __float_as_int(w.x));
    pairs[p1] = make_int2(d.y, __float_as_int(w.y));
    pairs[p2] = make_int2(d.z, __float_as_int(w.z));
    pairs[p3] = make_int2(d.w, __float_as_int(w.w));
}

// ---------- gather: 1 node/wave, 4 lane-groups of 16, uint2 bf16 loads ----------
__global__ void lgcn_gather(const ushort* __restrict__ ego,
                            ushort* __restrict__ nego,
                            float* __restrict__ acc,
                            const int* __restrict__ rowPtr,
                            const int2* __restrict__ pairs,
                            float scale, int writeEgo) {
    int node = blockIdx.x * 4 + (threadIdx.x >> 6);
    int lane = threadIdx.x & 63;
    int g    = (lane >> 4) & 3;     // lane-group: owns edges beg+g, +4, +8, ...
    int sub  = lane & 15;           // 4 dims per lane: [4*sub, 4*sub+3]
    if (node >= N_NODES) return;
    int beg = rowPtr[node];
    int end = rowPtr[node + 1];

    float s0 = 0.f, s1 = 0.f, s2 = 0.f, s3 = 0.f;
    int i = beg + g;
    for (; i + 4 < end; i += 8) {           // unroll 2 per group
        int2 pa = pairs[i];
        int2 pb = pairs[i + 4];
        uint2 ra = *(const uint2*)(ego + ((size_t)pa.x << 6) + (sub << 2));
        uint2 rb = *(const uint2*)(ego + ((size_t)pb.x << 6) + (sub << 2));
        float wa = __int_as_float(pa.y);
        float wb = __int_as_float(pb.y);
        s0 += wa * bflo(ra.x);  s1 += wa * bfhi(ra.x);
        s2 += wa * bflo(ra.y);  s3 += wa * bfhi(ra.y);
        s0 += wb * bflo(rb.x);  s1 += wb * bfhi(rb.x);
        s2 += wb * bflo(rb.y);  s3 += wb * bfhi(rb.y);
    }
    for (; i < end; i += 4) {
        int2 p = pairs[i];
        uint2 r = *(const uint2*)(ego + ((size_t)p.x << 6) + (sub << 2));
        float w = __int_as_float(p.y);
        s0 += w * bflo(r.x);  s1 += w * bfhi(r.x);
        s2 += w * bflo(r.y);  s3 += w * bfhi(r.y);
    }

    // combine the 4 lane-groups: lanes 0-15 end with the full sums
    s0 += __shfl_down(s0, 32); s1 += __shfl_down(s1, 32);
    s2 += __shfl_down(s2, 32); s3 += __shfl_down(s3, 32);
    s0 += __shfl_down(s0, 16); s1 += __shfl_down(s1, 16);
    s2 += __shfl_down(s2, 16); s3 += __shfl_down(s3, 16);

    if (lane < 16) {
        float4* ap = (float4*)(acc + ((size_t)node << 6));
        float4 a = ap[lane];
        a.x = (a.x + s0) * scale;
        a.y = (a.y + s1) * scale;
        a.z = (a.z + s2) * scale;
        a.w = (a.w + s3) * scale;
        ap[lane] = a;
        if (writeEgo) {
            uint2* np = (uint2*)(nego + ((size_t)node << 6));
            np[lane] = make_uint2(pack2_bf16(s0, s1), pack2_bf16(s2, s3));
        }
    }
}

extern "C" void kernel_launch(void* const* d_in, const int* in_sizes, int n_in,
                              void* d_out, int out_size, void* d_ws, size_t ws_size,
                              hipStream_t stream) {
    const float* user_emb  = (const float*)d_in[0];
    const float* item_emb  = (const float*)d_in[1];
    const float* edge_norm = (const float*)d_in[2];
    const int*   edge_src  = (const int*)d_in[3];
    const int*   edge_dst  = (const int*)d_in[4];
    float* acc = (float*)d_out;

    char* w = (char*)d_ws;
    ushort* egoA  = (ushort*)w;                        w += (size_t)NODE_FLOATS * 2;   // 19.2 MB bf16
    ushort* egoB  = (ushort*)w;                        w += (size_t)NODE_FLOATS * 2;   // 19.2 MB bf16
    int2*  pairs  = (int2*)w;                          w += (size_t)N_EDGES * 8;       // 16 MB
    int*   rowPtr = (int*)w;                           w += (size_t)(N_NODES + 4) * 4;
    int*   cursor = (int*)w;                           w += (size_t)N_NODES * 4;
    int*   counts = (int*)w;                           w += (size_t)N_NODES * 4;
    int*   blkSum = (int*)w;

    const int T = 256;
    const int EW_BLOCKS = 2048;
    const int E4_BLOCKS = (N_EDGES / 4 + T - 1) / T;   // 1954
    const int GATHER_BLOCKS = (N_NODES + 3) / 4;       // 37500, 1 node/wave

    lgcn_init<<<EW_BLOCKS, T, 0, stream>>>(
        (const float4*)user_emb, (const float4*)item_emb,
        (uint2*)egoA, (float4*)acc);

    zero_ints<<<(N_NODES + T - 1) / T, T, 0, stream>>>(counts, N_NODES);
    hist_src<<<E4_BLOCKS, T, 0, stream>>>(edge_src, counts);
    scan_blocks<<<NBLK, SCAN_BLK, 0, stream>>>(counts, rowPtr, blkSum);
    scan_tops<<<1, 1024, 0, stream>>>(blkSum);
    add_offsets<<<NBLK, SCAN_BLK, 0, stream>>>(rowPtr, cursor, blkSum);
    fill_pairs<<<E4_BLOCKS, T, 0, stream>>>(edge_src, edge_dst, edge_norm, cursor, pairs);

    // Layer 1: A -> B, acc += B
    lgcn_gather<<<GATHER_BLOCKS, T, 0, stream>>>(egoA, egoB, acc, rowPtr, pairs, 1.0f, 1);
    // Layer 2: B -> A, acc += A
    lgcn_gather<<<GATHER_BLOCKS, T, 0, stream>>>(egoB, egoA, acc, rowPtr, pairs, 1.0f, 1);
    // Layer 3: A -> (none), acc = (acc + ego3) * 0.25
    lgcn_gather<<<GATHER_BLOCKS, T, 0, stream>>>(egoA, egoB, acc, rowPtr, pairs, 0.25f, 0);
}

// Round 4
// 496.199 us; speedup vs baseline: 10.5156x; 1.0834x over previous
//
#include <hip/hip_runtime.h>

// LightGCN 3-layer propagation, pull-based CSR, bf16 ego intermediates.
// Round 4: split atomic-rank (hist) from the scatter store (fill), both
// latency-optimized; gather unrolled x4; init no longer writes acc.

#define NUM_USERS 100000
#define NUM_ITEMS 50000
#define EMB_DIM   64
#define N_EDGES   2000000
#define N_NODES   (NUM_USERS + NUM_ITEMS)          // 150000
#define NODE_FLOATS (N_NODES * EMB_DIM)            // 9,600,000
#define NODE_F4     (NODE_FLOATS / 4)              // 2,400,000
#define SCAN_BLK    256
#define NBLK        ((N_NODES + SCAN_BLK - 1) / SCAN_BLK)   // 586

typedef unsigned int uint;
typedef unsigned short ushort;
typedef unsigned long long u64;

__device__ __forceinline__ uint pack2_bf16(float a, float b) {
    uint ua = __float_as_uint(a), ub = __float_as_uint(b);
    ua += 0x7FFFu + ((ua >> 16) & 1u);      // RNE
    ub += 0x7FFFu + ((ub >> 16) & 1u);
    return (ua >> 16) | (ub & 0xFFFF0000u);
}
__device__ __forceinline__ float bflo(uint u) { return __uint_as_float(u << 16); }
__device__ __forceinline__ float bfhi(uint u) { return __uint_as_float(u & 0xFFFF0000u); }

// ---------- init: egoA(bf16) = concat(user,item) ----------
__global__ void lgcn_init(const float4* __restrict__ user,
                          const float4* __restrict__ item,
                          uint2* __restrict__ egoA) {
    const int n_user4 = NUM_USERS * EMB_DIM / 4;
    for (int i = blockIdx.x * blockDim.x + threadIdx.x; i < NODE_F4;
         i += gridDim.x * blockDim.x) {
        float4 v = (i < n_user4) ? user[i] : item[i - n_user4];
        egoA[i] = make_uint2(pack2_bf16(v.x, v.y), pack2_bf16(v.z, v.w));
    }
}

// ---------- CSR build ----------
__global__ void zero_ints(int* __restrict__ p, int n) {
    for (int i = blockIdx.x * blockDim.x + threadIdx.x; i < n;
         i += gridDim.x * blockDim.x)
        p[i] = 0;
}

// hist + rank in one: atomics have no dependent random store, ranks coalesced
__global__ void hist_src(const int* __restrict__ src,
                         int* __restrict__ counts,
                         int* __restrict__ rank) {
    int base = (blockIdx.x * blockDim.x + threadIdx.x) * 4;
    if (base >= N_EDGES) return;
    int4 s = *(const int4*)(src + base);
    int4 r;
    r.x = atomicAdd(&counts[s.x], 1);
    r.y = atomicAdd(&counts[s.y], 1);
    r.z = atomicAdd(&counts[s.z], 1);
    r.w = atomicAdd(&counts[s.w], 1);
    *(int4*)(rank + base) = r;
}

__global__ void scan_blocks(const int* __restrict__ counts,
                            int* __restrict__ rowPtr,
                            int* __restrict__ blkSum) {
    __shared__ int s[SCAN_BLK];
    int t = threadIdx.x;
    int i = blockIdx.x * SCAN_BLK + t;
    int v = (i < N_NODES) ? counts[i] : 0;
    s[t] = v;
    __syncthreads();
    for (int off = 1; off < SCAN_BLK; off <<= 1) {
        int x = (t >= off) ? s[t - off] : 0;
        __syncthreads();
        s[t] += x;
        __syncthreads();
    }
    if (i < N_NODES) rowPtr[i] = s[t] - v;
    if (t == SCAN_BLK - 1) blkSum[blockIdx.x] = s[t];
}

__global__ void scan_tops(int* __restrict__ blkSum) {
    __shared__ int s[1024];
    int t = threadIdx.x;
    int v = (t < NBLK) ? blkSum[t] : 0;
    s[t] = v;
    __syncthreads();
    for (int off = 1; off < 1024; off <<= 1) {
        int x = (t >= off) ? s[t - off] : 0;
        __syncthreads();
        s[t] += x;
        __syncthreads();
    }
    if (t < NBLK) blkSum[t] = s[t] - v;
}

__global__ void add_offsets(int* __restrict__ rowPtr,
                            const int* __restrict__ blkSum) {
    int i = blockIdx.x * SCAN_BLK + threadIdx.x;
    if (i < N_NODES) rowPtr[i] += blkSum[blockIdx.x];
    if (i == 0) rowPtr[N_NODES] = N_EDGES;
}

// atomic-free scatter: pos = rowPtr[src] + rank; 1 edge/thread (max waves)
__global__ void fill_pairs(const int* __restrict__ src,
                           const int* __restrict__ dst,
                           const float* __restrict__ norm,
                           const int* __restrict__ rank,
                           const int* __restrict__ rowPtr,
                           u64* __restrict__ pairs) {
    int e = blockIdx.x * blockDim.x + threadIdx.x;
    if (e >= N_EDGES) return;
    int s = src[e];
    int r = rank[e];
    int d = dst[e];
    float w = norm[e];
    int pos = rowPtr[s] + r;
    u64 packed = (u64)(uint)d | ((u64)(uint)__float_as_uint(w) << 32);
    __builtin_nontemporal_store(packed, &pairs[pos]);   // keep rowPtr hot in L2
}

// ---------- gather: 1 node/wave, 4 lane-groups of 16, unroll 4 ----------
__global__ void lgcn_gather(const ushort* __restrict__ ego,
                            ushort* __restrict__ nego,
                            float* __restrict__ acc,
                            const ushort* __restrict__ ego0,   // layer-1 acc seed
                            const int* __restrict__ rowPtr,
                            const int2* __restrict__ pairs,
                            float scale, int writeEgo, int accFromEgo0) {
    int node = blockIdx.x * 4 + (threadIdx.x >> 6);
    int lane = threadIdx.x & 63;
    int g    = (lane >> 4) & 3;     // lane-group: owns edges beg+g, +4, +8, ...
    int sub  = lane & 15;           // 4 dims per lane
    if (node >= N_NODES) return;
    int beg = rowPtr[node];
    int end = rowPtr[node + 1];

    float s0 = 0.f, s1 = 0.f, s2 = 0.f, s3 = 0.f;
    int i = beg + g;
    for (; i + 12 < end; i += 16) {         // 4 edges in flight per group
        int2 pa = pairs[i];
        int2 pb = pairs[i + 4];
        int2 pc = pairs[i + 8];
        int2 pd = pairs[i + 12];
        uint2 ra = *(const uint2*)(ego + ((size_t)pa.x << 6) + (sub << 2));
        uint2 rb = *(const uint2*)(ego + ((size_t)pb.x << 6) + (sub << 2));
        uint2 rc = *(const uint2*)(ego + ((size_t)pc.x << 6) + (sub << 2));
        uint2 rd = *(const uint2*)(ego + ((size_t)pd.x << 6) + (sub << 2));
        float wa = __int_as_float(pa.y), wb = __int_as_float(pb.y);
        float wc = __int_as_float(pc.y), wd = __int_as_float(pd.y);
        s0 += wa * bflo(ra.x);  s1 += wa * bfhi(ra.x);
        s2 += wa * bflo(ra.y);  s3 += wa * bfhi(ra.y);
        s0 += wb * bflo(rb.x);  s1 += wb * bfhi(rb.x);
        s2 += wb * bflo(rb.y);  s3 += wb * bfhi(rb.y);
        s0 += wc * bflo(rc.x);  s1 += wc * bfhi(rc.x);
        s2 += wc * bflo(rc.y);  s3 += wc * bfhi(rc.y);
        s0 += wd * bflo(rd.x);  s1 += wd * bfhi(rd.x);
        s2 += wd * bflo(rd.y);  s3 += wd * bfhi(rd.y);
    }
    for (; i < end; i += 4) {
        int2 p = pairs[i];
        uint2 r = *(const uint2*)(ego + ((size_t)p.x << 6) + (sub << 2));
        float w = __int_as_float(p.y);
        s0 += w * bflo(r.x);  s1 += w * bfhi(r.x);
        s2 += w * bflo(r.y);  s3 += w * bfhi(r.y);
    }

    s0 += __shfl_down(s0, 32); s1 += __shfl_down(s1, 32);
    s2 += __shfl_down(s2, 32); s3 += __shfl_down(s3, 32);
    s0 += __shfl_down(s0, 16); s1 += __shfl_down(s1, 16);
    s2 += __shfl_down(s2, 16); s3 += __shfl_down(s3, 16);

    if (lane < 16) {
        float4* ap = (float4*)(acc + ((size_t)node << 6));
        float4 a;
        if (accFromEgo0) {
            uint2 z = *(const uint2*)(ego0 + ((size_t)node << 6) + (lane << 2));
            a = make_float4(bflo(z.x), bfhi(z.x), bflo(z.y), bfhi(z.y));
        } else {
            a = ap[lane];
        }
        a.x = (a.x + s0) * scale;
        a.y = (a.y + s1) * scale;
        a.z = (a.z + s2) * scale;
        a.w = (a.w + s3) * scale;
        ap[lane] = a;
        if (writeEgo) {
            uint2* np = (uint2*)(nego + ((size_t)node << 6));
            np[lane] = make_uint2(pack2_bf16(s0, s1), pack2_bf16(s2, s3));
        }
    }
}

extern "C" void kernel_launch(void* const* d_in, const int* in_sizes, int n_in,
                              void* d_out, int out_size, void* d_ws, size_t ws_size,
                              hipStream_t stream) {
    const float* user_emb  = (const float*)d_in[0];
    const float* item_emb  = (const float*)d_in[1];
    const float* edge_norm = (const float*)d_in[2];
    const int*   edge_src  = (const int*)d_in[3];
    const int*   edge_dst  = (const int*)d_in[4];
    float* acc = (float*)d_out;

    char* w = (char*)d_ws;
    ushort* egoA  = (ushort*)w;                        w += (size_t)NODE_FLOATS * 2;   // 19.2 MB
    ushort* egoB  = (ushort*)w;                        w += (size_t)NODE_FLOATS * 2;   // 19.2 MB
    u64*   pairs  = (u64*)w;                           w += (size_t)N_EDGES * 8;       // 16 MB
    int*   rank   = (int*)w;                           w += (size_t)N_EDGES * 4;       // 8 MB
    int*   rowPtr = (int*)w;                           w += (size_t)(N_NODES + 4) * 4;
    int*   counts = (int*)w;                           w += (size_t)N_NODES * 4;
    int*   blkSum = (int*)w;

    const int T = 256;
    const int EW_BLOCKS = 2048;
    const int E4_BLOCKS = (N_EDGES / 4 + T - 1) / T;   // 1954
    const int E1_BLOCKS = (N_EDGES + T - 1) / T;       // 7813
    const int GATHER_BLOCKS = (N_NODES + 3) / 4;       // 37500

    lgcn_init<<<EW_BLOCKS, T, 0, stream>>>(
        (const float4*)user_emb, (const float4*)item_emb, (uint2*)egoA);

    zero_ints<<<(N_NODES + T - 1) / T, T, 0, stream>>>(counts, N_NODES);
    hist_src<<<E4_BLOCKS, T, 0, stream>>>(edge_src, counts, rank);
    scan_blocks<<<NBLK, SCAN_BLK, 0, stream>>>(counts, rowPtr, blkSum);
    scan_tops<<<1, 1024, 0, stream>>>(blkSum);
    add_offsets<<<NBLK, SCAN_BLK, 0, stream>>>(rowPtr, blkSum);
    fill_pairs<<<E1_BLOCKS, T, 0, stream>>>(edge_src, edge_dst, edge_norm,
                                            rank, rowPtr, pairs);

    // Layer 1: A -> B, acc = ego0 + B   (ego0 read from egoA, bf16)
    lgcn_gather<<<GATHER_BLOCKS, T, 0, stream>>>(egoA, egoB, acc, egoA,
                                                 rowPtr, (const int2*)pairs, 1.0f, 1, 1);
    // Layer 2: B -> A, acc += A
    lgcn_gather<<<GATHER_BLOCKS, T, 0, stream>>>(egoB, egoA, acc, egoA,
                                                 rowPtr, (const int2*)pairs, 1.0f, 1, 0);
    // Layer 3: A -> (none), acc = (acc + ego3) * 0.25
    lgcn_gather<<<GATHER_BLOCKS, T, 0, stream>>>(egoA, egoB, acc, egoA,
                                                 rowPtr, (const int2*)pairs, 0.25f, 0, 0);
}

// Round 5
// 442.170 us; speedup vs baseline: 11.8005x; 1.1222x over previous
//
#include <hip/hip_runtime.h>

// LightGCN 3-layer propagation, pull-based CSR, bf16 ego intermediates.
// Round 5: CSR build via locality-preserving two-level bucket sort
// (bucket = src/293, 512 buckets) — replaces hist+rank+random-fill, whose
// 8B random stores caused 8x write amplification (125MB for 16MB payload).

#define NUM_USERS 100000
#define NUM_ITEMS 50000
#define EMB_DIM   64
#define N_EDGES   2000000
#define N_NODES   (NUM_USERS + NUM_ITEMS)          // 150000
#define NODE_FLOATS (N_NODES * EMB_DIM)            // 9,600,000
#define NODE_F4     (NODE_FLOATS / 4)              // 2,400,000

#define NBUCKET  512
#define NPB      293        // nodes per bucket; 512*293 = 150016 >= 150000
#define VPT      32         // edges per thread in bucket passes
#define TILE     (256 * VPT)                        // 8192
#define NTILE    ((N_EDGES + TILE - 1) / TILE)      // 245

typedef unsigned int uint;
typedef unsigned short ushort;
typedef unsigned long long u64;

__device__ __forceinline__ uint pack2_bf16(float a, float b) {
    uint ua = __float_as_uint(a), ub = __float_as_uint(b);
    ua += 0x7FFFu + ((ua >> 16) & 1u);      // RNE
    ub += 0x7FFFu + ((ub >> 16) & 1u);
    return (ua >> 16) | (ub & 0xFFFF0000u);
}
__device__ __forceinline__ float bflo(uint u) { return __uint_as_float(u << 16); }
__device__ __forceinline__ float bfhi(uint u) { return __uint_as_float(u & 0xFFFF0000u); }

// ---------- init: egoA(bf16) = concat(user,item) ----------
__global__ void lgcn_init(const float4* __restrict__ user,
                          const float4* __restrict__ item,
                          uint2* __restrict__ egoA) {
    const int n_user4 = NUM_USERS * EMB_DIM / 4;
    for (int i = blockIdx.x * blockDim.x + threadIdx.x; i < NODE_F4;
         i += gridDim.x * blockDim.x) {
        float4 v = (i < n_user4) ? user[i] : item[i - n_user4];
        egoA[i] = make_uint2(pack2_bf16(v.x, v.y), pack2_bf16(v.z, v.w));
    }
}

__global__ void zero_ints(int* __restrict__ p, int n) {
    int i = blockIdx.x * blockDim.x + threadIdx.x;
    if (i < n) p[i] = 0;
}

// ---------- pass A: coarse histogram (LDS-reduced) ----------
__global__ void bucket_hist(const int* __restrict__ src,
                            int* __restrict__ bucketCount) {
    __shared__ int cnt[NBUCKET];
    int t = threadIdx.x;
    cnt[t] = 0; cnt[t + 256] = 0;
    __syncthreads();
    int base = blockIdx.x * TILE + t;
    #pragma unroll 4
    for (int k = 0; k < VPT; ++k) {
        int e = base + k * 256;
        if (e < N_EDGES) atomicAdd(&cnt[src[e] / NPB], 1);
    }
    __syncthreads();
    int c0 = cnt[t], c1 = cnt[t + 256];
    if (c0) atomicAdd(&bucketCount[t], c0);
    if (c1) atomicAdd(&bucketCount[t + 256], c1);
}

// ---------- scan over 512 buckets (1 block, 512 threads) ----------
__global__ void bucket_scan(const int* __restrict__ bucketCount,
                            int* __restrict__ bucketOffset,
                            int* __restrict__ gCur,
                            int* __restrict__ rowPtr) {
    __shared__ int s[NBUCKET];
    int t = threadIdx.x;
    int v = bucketCount[t];
    s[t] = v;
    __syncthreads();
    for (int off = 1; off < NBUCKET; off <<= 1) {
        int x = (t >= off) ? s[t - off] : 0;
        __syncthreads();
        s[t] += x;
        __syncthreads();
    }
    int excl = s[t] - v;
    bucketOffset[t] = excl;
    gCur[t] = excl;
    if (t == 0) {
        bucketOffset[NBUCKET] = N_EDGES;
        rowPtr[N_NODES] = N_EDGES;
    }
}

// ---------- pass B: scatter edges into bucket-contiguous runs ----------
__global__ void bucket_scatter(const int* __restrict__ src,
                               const int* __restrict__ dst,
                               const float* __restrict__ norm,
                               int* __restrict__ gCur,
                               int* __restrict__ bsrc,
                               u64* __restrict__ bpair) {
    __shared__ int cnt[NBUCKET];
    __shared__ int bbase[NBUCKET];
    int t = threadIdx.x;
    cnt[t] = 0; cnt[t + 256] = 0;
    __syncthreads();
    int base = blockIdx.x * TILE + t;
    #pragma unroll 4
    for (int k = 0; k < VPT; ++k) {
        int e = base + k * 256;
        if (e < N_EDGES) atomicAdd(&cnt[src[e] / NPB], 1);
    }
    __syncthreads();
    // reserve per-bucket runs for this tile
    for (int b = t; b < NBUCKET; b += 256) {
        int c = cnt[b];
        bbase[b] = c ? atomicAdd(&gCur[b], c) : 0;
    }
    __syncthreads();
    cnt[t] = 0; cnt[t + 256] = 0;
    __syncthreads();
    #pragma unroll 4
    for (int k = 0; k < VPT; ++k) {
        int e = base + k * 256;
        if (e < N_EDGES) {
            int s = src[e];
            int b = s / NPB;
            int r = atomicAdd(&cnt[b], 1);
            int pos = bbase[b] + r;
            bsrc[pos]  = s;
            bpair[pos] = (u64)(uint)dst[e] | ((u64)(uint)__float_as_uint(norm[e]) << 32);
        }
    }
}

// ---------- pass C: per-bucket CSR finalize (rowPtr + placed pairs) ----------
__global__ void csr_finalize(const int* __restrict__ bucketOffset,
                             const int* __restrict__ bsrc,
                             const u64* __restrict__ bpair,
                             int* __restrict__ rowPtr,
                             u64* __restrict__ pairs) {
    __shared__ int cnt[512];
    __shared__ int cur[512];
    int b = blockIdx.x;
    int t = threadIdx.x;          // 512 threads
    int beg = bucketOffset[b];
    int end = bucketOffset[b + 1];
    int nodeBase = b * NPB;

    cnt[t] = 0;
    __syncthreads();
    for (int i = beg + t; i < end; i += 512)
        atomicAdd(&cnt[bsrc[i] - nodeBase], 1);
    __syncthreads();
    int v = cnt[t];
    for (int off = 1; off < 512; off <<= 1) {     // inclusive scan
        int x = (t >= off) ? cnt[t - off] : 0;
        __syncthreads();
        cnt[t] += x;
        __syncthreads();
    }
    int excl = cnt[t] - v;
    cur[t] = excl;
    int node = nodeBase + t;
    if (t < NPB && node < N_NODES) rowPtr[node] = beg + excl;
    __syncthreads();
    for (int i = beg + t; i < end; i += 512) {
        int s = bsrc[i] - nodeBase;
        int r = atomicAdd(&cur[s], 1);
        pairs[beg + r] = bpair[i];
    }
}

// ---------- gather: 1 node/wave, 4 lane-groups of 16, unroll 4 ----------
__global__ void lgcn_gather(const ushort* __restrict__ ego,
                            ushort* __restrict__ nego,
                            float* __restrict__ acc,
                            const ushort* __restrict__ ego0,
                            const int* __restrict__ rowPtr,
                            const int2* __restrict__ pairs,
                            float scale, int writeEgo, int accFromEgo0) {
    int node = blockIdx.x * 4 + (threadIdx.x >> 6);
    int lane = threadIdx.x & 63;
    int g    = (lane >> 4) & 3;
    int sub  = lane & 15;
    if (node >= N_NODES) return;
    int beg = rowPtr[node];
    int end = rowPtr[node + 1];

    float s0 = 0.f, s1 = 0.f, s2 = 0.f, s3 = 0.f;
    int i = beg + g;
    for (; i + 12 < end; i += 16) {
        int2 pa = pairs[i];
        int2 pb = pairs[i + 4];
        int2 pc = pairs[i + 8];
        int2 pd = pairs[i + 12];
        uint2 ra = *(const uint2*)(ego + ((size_t)pa.x << 6) + (sub << 2));
        uint2 rb = *(const uint2*)(ego + ((size_t)pb.x << 6) + (sub << 2));
        uint2 rc = *(const uint2*)(ego + ((size_t)pc.x << 6) + (sub << 2));
        uint2 rd = *(const uint2*)(ego + ((size_t)pd.x << 6) + (sub << 2));
        float wa = __int_as_float(pa.y), wb = __int_as_float(pb.y);
        float wc = __int_as_float(pc.y), wd = __int_as_float(pd.y);
        s0 += wa * bflo(ra.x);  s1 += wa * bfhi(ra.x);
        s2 += wa * bflo(ra.y);  s3 += wa * bfhi(ra.y);
        s0 += wb * bflo(rb.x);  s1 += wb * bfhi(rb.x);
        s2 += wb * bflo(rb.y);  s3 += wb * bfhi(rb.y);
        s0 += wc * bflo(rc.x);  s1 += wc * bfhi(rc.x);
        s2 += wc * bflo(rc.y);  s3 += wc * bfhi(rc.y);
        s0 += wd * bflo(rd.x);  s1 += wd * bfhi(rd.x);
        s2 += wd * bflo(rd.y);  s3 += wd * bfhi(rd.y);
    }
    for (; i < end; i += 4) {
        int2 p = pairs[i];
        uint2 r = *(const uint2*)(ego + ((size_t)p.x << 6) + (sub << 2));
        float w = __int_as_float(p.y);
        s0 += w * bflo(r.x);  s1 += w * bfhi(r.x);
        s2 += w * bflo(r.y);  s3 += w * bfhi(r.y);
    }

    s0 += __shfl_down(s0, 32); s1 += __shfl_down(s1, 32);
    s2 += __shfl_down(s2, 32); s3 += __shfl_down(s3, 32);
    s0 += __shfl_down(s0, 16); s1 += __shfl_down(s1, 16);
    s2 += __shfl_down(s2, 16); s3 += __shfl_down(s3, 16);

    if (lane < 16) {
        float4* ap = (float4*)(acc + ((size_t)node << 6));
        float4 a;
        if (accFromEgo0) {
            uint2 z = *(const uint2*)(ego0 + ((size_t)node << 6) + (lane << 2));
            a = make_float4(bflo(z.x), bfhi(z.x), bflo(z.y), bfhi(z.y));
        } else {
            a = ap[lane];
        }
        a.x = (a.x + s0) * scale;
        a.y = (a.y + s1) * scale;
        a.z = (a.z + s2) * scale;
        a.w = (a.w + s3) * scale;
        ap[lane] = a;
        if (writeEgo) {
            uint2* np = (uint2*)(nego + ((size_t)node << 6));
            np[lane] = make_uint2(pack2_bf16(s0, s1), pack2_bf16(s2, s3));
        }
    }
}

extern "C" void kernel_launch(void* const* d_in, const int* in_sizes, int n_in,
                              void* d_out, int out_size, void* d_ws, size_t ws_size,
                              hipStream_t stream) {
    const float* user_emb  = (const float*)d_in[0];
    const float* item_emb  = (const float*)d_in[1];
    const float* edge_norm = (const float*)d_in[2];
    const int*   edge_src  = (const int*)d_in[3];
    const int*   edge_dst  = (const int*)d_in[4];
    float* acc = (float*)d_out;

    char* w = (char*)d_ws;
    ushort* egoA  = (ushort*)w;                      w += (size_t)NODE_FLOATS * 2;   // 19.2 MB
    ushort* egoB  = (ushort*)w;                      w += (size_t)NODE_FLOATS * 2;   // 19.2 MB
    u64*   pairs  = (u64*)w;                         w += (size_t)N_EDGES * 8;       // 16 MB
    u64*   bpair  = (u64*)w;                         w += (size_t)N_EDGES * 8;       // 16 MB
    int*   bsrc   = (int*)w;                         w += (size_t)N_EDGES * 4;       // 8 MB
    int*   rowPtr = (int*)w;                         w += (size_t)(N_NODES + 4) * 4;
    int*   bucketCount  = (int*)w;                   w += (size_t)NBUCKET * 4;
    int*   bucketOffset = (int*)w;                   w += (size_t)(NBUCKET + 4) * 4;
    int*   gCur   = (int*)w;

    const int T = 256;
    const int EW_BLOCKS = 2048;
    const int GATHER_BLOCKS = (N_NODES + 3) / 4;     // 37500

    lgcn_init<<<EW_BLOCKS, T, 0, stream>>>(
        (const float4*)user_emb, (const float4*)item_emb, (uint2*)egoA);

    zero_ints<<<2, T, 0, stream>>>(bucketCount, NBUCKET);
    bucket_hist<<<NTILE, T, 0, stream>>>(edge_src, bucketCount);
    bucket_scan<<<1, NBUCKET, 0, stream>>>(bucketCount, bucketOffset, gCur, rowPtr);
    bucket_scatter<<<NTILE, T, 0, stream>>>(edge_src, edge_dst, edge_norm,
                                            gCur, bsrc, bpair);
    csr_finalize<<<NBUCKET, 512, 0, stream>>>(bucketOffset, bsrc, bpair,
                                              rowPtr, pairs);

    // Layer 1: A -> B, acc = ego0 + B
    lgcn_gather<<<GATHER_BLOCKS, T, 0, stream>>>(egoA, egoB, acc, egoA,
                                                 rowPtr, (const int2*)pairs, 1.0f, 1, 1);
    // Layer 2: B -> A, acc += A
    lgcn_gather<<<GATHER_BLOCKS, T, 0, stream>>>(egoB, egoA, acc, egoA,
                                                 rowPtr, (const int2*)pairs, 1.0f, 1, 0);
    // Layer 3: A -> (none), acc = (acc + ego3) * 0.25
    lgcn_gather<<<GATHER_BLOCKS, T, 0, stream>>>(egoA, egoB, acc, egoA,
                                                 rowPtr, (const int2*)pairs, 0.25f, 0, 0);
}

// Round 6
// 440.656 us; speedup vs baseline: 11.8410x; 1.0034x over previous
//
#include <hip/hip_runtime.h>

// LightGCN 3-layer propagation, pull-based CSR, bf16 ego intermediates.
// Round 6: occupancy fix for the CSR-build kernels. bucket_scatter/hist go
// 512thr x VPT8 (489 blocks, ~50% occ vs 9%); csr_finalize goes 1024 threads
// (full CU occupancy). Pipeline shape unchanged from round 5.

#define NUM_USERS 100000
#define NUM_ITEMS 50000
#define EMB_DIM   64
#define N_EDGES   2000000
#define N_NODES   (NUM_USERS + NUM_ITEMS)          // 150000
#define NODE_FLOATS (N_NODES * EMB_DIM)            // 9,600,000
#define NODE_F4     (NODE_FLOATS / 4)              // 2,400,000

#define NBUCKET  512
#define NPB      293        // nodes per bucket; 512*293 = 150016 >= 150000
#define BT       512        // threads in bucket passes
#define VPT      8          // edges per thread in bucket passes
#define TILE     (BT * VPT)                         // 4096
#define NTILE    ((N_EDGES + TILE - 1) / TILE)      // 489

typedef unsigned int uint;
typedef unsigned short ushort;
typedef unsigned long long u64;

__device__ __forceinline__ uint pack2_bf16(float a, float b) {
    uint ua = __float_as_uint(a), ub = __float_as_uint(b);
    ua += 0x7FFFu + ((ua >> 16) & 1u);      // RNE
    ub += 0x7FFFu + ((ub >> 16) & 1u);
    return (ua >> 16) | (ub & 0xFFFF0000u);
}
__device__ __forceinline__ float bflo(uint u) { return __uint_as_float(u << 16); }
__device__ __forceinline__ float bfhi(uint u) { return __uint_as_float(u & 0xFFFF0000u); }

// ---------- init: egoA(bf16) = concat(user,item) ----------
__global__ void lgcn_init(const float4* __restrict__ user,
                          const float4* __restrict__ item,
                          uint2* __restrict__ egoA) {
    const int n_user4 = NUM_USERS * EMB_DIM / 4;
    for (int i = blockIdx.x * blockDim.x + threadIdx.x; i < NODE_F4;
         i += gridDim.x * blockDim.x) {
        float4 v = (i < n_user4) ? user[i] : item[i - n_user4];
        egoA[i] = make_uint2(pack2_bf16(v.x, v.y), pack2_bf16(v.z, v.w));
    }
}

__global__ void zero_ints(int* __restrict__ p, int n) {
    int i = blockIdx.x * blockDim.x + threadIdx.x;
    if (i < n) p[i] = 0;
}

// ---------- pass A: coarse histogram (LDS-reduced) ----------
__global__ __launch_bounds__(BT) void bucket_hist(const int* __restrict__ src,
                                                  int* __restrict__ bucketCount) {
    __shared__ int cnt[NBUCKET];
    int t = threadIdx.x;
    cnt[t] = 0;
    __syncthreads();
    int base = blockIdx.x * TILE + t;
    #pragma unroll
    for (int k = 0; k < VPT; ++k) {
        int e = base + k * BT;
        if (e < N_EDGES) atomicAdd(&cnt[src[e] / NPB], 1);
    }
    __syncthreads();
    int c = cnt[t];
    if (c) atomicAdd(&bucketCount[t], c);
}

// ---------- scan over 512 buckets (1 block, 512 threads) ----------
__global__ void bucket_scan(const int* __restrict__ bucketCount,
                            int* __restrict__ bucketOffset,
                            int* __restrict__ gCur,
                            int* __restrict__ rowPtr) {
    __shared__ int s[NBUCKET];
    int t = threadIdx.x;
    int v = bucketCount[t];
    s[t] = v;
    __syncthreads();
    for (int off = 1; off < NBUCKET; off <<= 1) {
        int x = (t >= off) ? s[t - off] : 0;
        __syncthreads();
        s[t] += x;
        __syncthreads();
    }
    int excl = s[t] - v;
    bucketOffset[t] = excl;
    gCur[t] = excl;
    if (t == 0) {
        bucketOffset[NBUCKET] = N_EDGES;
        rowPtr[N_NODES] = N_EDGES;
    }
}

// ---------- pass B: scatter edges into bucket-contiguous runs ----------
__global__ __launch_bounds__(BT) void bucket_scatter(const int* __restrict__ src,
                                                     const int* __restrict__ dst,
                                                     const float* __restrict__ norm,
                                                     int* __restrict__ gCur,
                                                     int* __restrict__ bsrc,
                                                     u64* __restrict__ bpair) {
    __shared__ int cnt[NBUCKET];
    __shared__ int bbase[NBUCKET];
    int t = threadIdx.x;
    cnt[t] = 0;
    __syncthreads();
    int base = blockIdx.x * TILE + t;
    #pragma unroll
    for (int k = 0; k < VPT; ++k) {
        int e = base + k * BT;
        if (e < N_EDGES) atomicAdd(&cnt[src[e] / NPB], 1);
    }
    __syncthreads();
    int c = cnt[t];
    bbase[t] = c ? atomicAdd(&gCur[t], c) : 0;
    __syncthreads();
    cnt[t] = 0;
    __syncthreads();
    #pragma unroll
    for (int k = 0; k < VPT; ++k) {
        int e = base + k * BT;
        if (e < N_EDGES) {
            int s = src[e];
            int b = s / NPB;
            int r = atomicAdd(&cnt[b], 1);
            int pos = bbase[b] + r;
            bsrc[pos]  = s;
            bpair[pos] = (u64)(uint)dst[e] | ((u64)(uint)__float_as_uint(norm[e]) << 32);
        }
    }
}

// ---------- pass C: per-bucket CSR finalize (1024 thr, full occupancy) ----------
__global__ __launch_bounds__(1024) void csr_finalize(const int* __restrict__ bucketOffset,
                                                     const int* __restrict__ bsrc,
                                                     const u64* __restrict__ bpair,
                                                     int* __restrict__ rowPtr,
                                                     u64* __restrict__ pairs) {
    __shared__ int cnt[NBUCKET];
    __shared__ int cur[NBUCKET];
    int b = blockIdx.x;
    int t = threadIdx.x;          // 1024 threads
    int beg = bucketOffset[b];
    int end = bucketOffset[b + 1];
    int nodeBase = b * NPB;

    if (t < NBUCKET) cnt[t] = 0;
    __syncthreads();
    for (int i = beg + t; i < end; i += 1024)
        atomicAdd(&cnt[bsrc[i] - nodeBase], 1);
    __syncthreads();
    int v = (t < NBUCKET) ? cnt[t] : 0;
    for (int off = 1; off < NBUCKET; off <<= 1) {     // inclusive scan, 512-wide
        int x = (t >= off && t < NBUCKET) ? cnt[t - off] : 0;
        __syncthreads();
        if (t < NBUCKET) cnt[t] += x;
        __syncthreads();
    }
    if (t < NBUCKET) {
        int excl = cnt[t] - v;
        cur[t] = excl;
        int node = nodeBase + t;
        if (t < NPB && node < N_NODES) rowPtr[node] = beg + excl;
    }
    __syncthreads();
    for (int i = beg + t; i < end; i += 1024) {
        int s = bsrc[i] - nodeBase;
        int r = atomicAdd(&cur[s], 1);
        pairs[beg + r] = bpair[i];
    }
}

// ---------- gather: 1 node/wave, 4 lane-groups of 16, unroll 4 ----------
__global__ void lgcn_gather(const ushort* __restrict__ ego,
                            ushort* __restrict__ nego,
                            float* __restrict__ acc,
                            const ushort* __restrict__ ego0,
                            const int* __restrict__ rowPtr,
                            const int2* __restrict__ pairs,
                            float scale, int writeEgo, int accFromEgo0) {
    int node = blockIdx.x * 4 + (threadIdx.x >> 6);
    int lane = threadIdx.x & 63;
    int g    = (lane >> 4) & 3;
    int sub  = lane & 15;
    if (node >= N_NODES) return;
    int beg = rowPtr[node];
    int end = rowPtr[node + 1];

    float s0 = 0.f, s1 = 0.f, s2 = 0.f, s3 = 0.f;
    int i = beg + g;
    for (; i + 12 < end; i += 16) {
        int2 pa = pairs[i];
        int2 pb = pairs[i + 4];
        int2 pc = pairs[i + 8];
        int2 pd = pairs[i + 12];
        uint2 ra = *(const uint2*)(ego + ((size_t)pa.x << 6) + (sub << 2));
        uint2 rb = *(const uint2*)(ego + ((size_t)pb.x << 6) + (sub << 2));
        uint2 rc = *(const uint2*)(ego + ((size_t)pc.x << 6) + (sub << 2));
        uint2 rd = *(const uint2*)(ego + ((size_t)pd.x << 6) + (sub << 2));
        float wa = __int_as_float(pa.y), wb = __int_as_float(pb.y);
        float wc = __int_as_float(pc.y), wd = __int_as_float(pd.y);
        s0 += wa * bflo(ra.x);  s1 += wa * bfhi(ra.x);
        s2 += wa * bflo(ra.y);  s3 += wa * bfhi(ra.y);
        s0 += wb * bflo(rb.x);  s1 += wb * bfhi(rb.x);
        s2 += wb * bflo(rb.y);  s3 += wb * bfhi(rb.y);
        s0 += wc * bflo(rc.x);  s1 += wc * bfhi(rc.x);
        s2 += wc * bflo(rc.y);  s3 += wc * bfhi(rc.y);
        s0 += wd * bflo(rd.x);  s1 += wd * bfhi(rd.x);
        s2 += wd * bflo(rd.y);  s3 += wd * bfhi(rd.y);
    }
    for (; i < end; i += 4) {
        int2 p = pairs[i];
        uint2 r = *(const uint2*)(ego + ((size_t)p.x << 6) + (sub << 2));
        float w = __int_as_float(p.y);
        s0 += w * bflo(r.x);  s1 += w * bfhi(r.x);
        s2 += w * bflo(r.y);  s3 += w * bfhi(r.y);
    }

    s0 += __shfl_down(s0, 32); s1 += __shfl_down(s1, 32);
    s2 += __shfl_down(s2, 32); s3 += __shfl_down(s3, 32);
    s0 += __shfl_down(s0, 16); s1 += __shfl_down(s1, 16);
    s2 += __shfl_down(s2, 16); s3 += __shfl_down(s3, 16);

    if (lane < 16) {
        float4* ap = (float4*)(acc + ((size_t)node << 6));
        float4 a;
        if (accFromEgo0) {
            uint2 z = *(const uint2*)(ego0 + ((size_t)node << 6) + (lane << 2));
            a = make_float4(bflo(z.x), bfhi(z.x), bflo(z.y), bfhi(z.y));
        } else {
            a = ap[lane];
        }
        a.x = (a.x + s0) * scale;
        a.y = (a.y + s1) * scale;
        a.z = (a.z + s2) * scale;
        a.w = (a.w + s3) * scale;
        ap[lane] = a;
        if (writeEgo) {
            uint2* np = (uint2*)(nego + ((size_t)node << 6));
            np[lane] = make_uint2(pack2_bf16(s0, s1), pack2_bf16(s2, s3));
        }
    }
}

extern "C" void kernel_launch(void* const* d_in, const int* in_sizes, int n_in,
                              void* d_out, int out_size, void* d_ws, size_t ws_size,
                              hipStream_t stream) {
    const float* user_emb  = (const float*)d_in[0];
    const float* item_emb  = (const float*)d_in[1];
    const float* edge_norm = (const float*)d_in[2];
    const int*   edge_src  = (const int*)d_in[3];
    const int*   edge_dst  = (const int*)d_in[4];
    float* acc = (float*)d_out;

    char* w = (char*)d_ws;
    ushort* egoA  = (ushort*)w;                      w += (size_t)NODE_FLOATS * 2;   // 19.2 MB
    ushort* egoB  = (ushort*)w;                      w += (size_t)NODE_FLOATS * 2;   // 19.2 MB
    u64*   pairs  = (u64*)w;                         w += (size_t)N_EDGES * 8;       // 16 MB
    u64*   bpair  = (u64*)w;                         w += (size_t)N_EDGES * 8;       // 16 MB
    int*   bsrc   = (int*)w;                         w += (size_t)N_EDGES * 4;       // 8 MB
    int*   rowPtr = (int*)w;                         w += (size_t)(N_NODES + 4) * 4;
    int*   bucketCount  = (int*)w;                   w += (size_t)NBUCKET * 4;
    int*   bucketOffset = (int*)w;                   w += (size_t)(NBUCKET + 4) * 4;
    int*   gCur   = (int*)w;

    const int T = 256;
    const int EW_BLOCKS = 2048;
    const int GATHER_BLOCKS = (N_NODES + 3) / 4;     // 37500

    lgcn_init<<<EW_BLOCKS, T, 0, stream>>>(
        (const float4*)user_emb, (const float4*)item_emb, (uint2*)egoA);

    zero_ints<<<2, T, 0, stream>>>(bucketCount, NBUCKET);
    bucket_hist<<<NTILE, BT, 0, stream>>>(edge_src, bucketCount);
    bucket_scan<<<1, NBUCKET, 0, stream>>>(bucketCount, bucketOffset, gCur, rowPtr);
    bucket_scatter<<<NTILE, BT, 0, stream>>>(edge_src, edge_dst, edge_norm,
                                             gCur, bsrc, bpair);
    csr_finalize<<<NBUCKET, 1024, 0, stream>>>(bucketOffset, bsrc, bpair,
                                               rowPtr, pairs);

    // Layer 1: A -> B, acc = ego0 + B
    lgcn_gather<<<GATHER_BLOCKS, T, 0, stream>>>(egoA, egoB, acc, egoA,
                                                 rowPtr, (const int2*)pairs, 1.0f, 1, 1);
    // Layer 2: B -> A, acc += A
    lgcn_gather<<<GATHER_BLOCKS, T, 0, stream>>>(egoB, egoA, acc, egoA,
                                                 rowPtr, (const int2*)pairs, 1.0f, 1, 0);
    // Layer 3: A -> (none), acc = (acc + ego3) * 0.25
    lgcn_gather<<<GATHER_BLOCKS, T, 0, stream>>>(egoA, egoB, acc, egoA,
                                                 rowPtr, (const int2*)pairs, 0.25f, 0, 0);
}

// Round 7
// 415.155 us; speedup vs baseline: 12.5683x; 1.0614x over previous
//
#include <hip/hip_runtime.h>

// LightGCN 3-layer propagation, pull-based CSR, bf16 ego intermediates.
// Round 7: scatter is dirty-sector-eviction bound (WRITE_SIZE ~ dur across
// r4-r6). Fix: (1) single packed u64 stream (src_local|dst|norm), bsrc
// deleted; (2) per-bucket reservations partitioned by blockIdx&7 so each
// sub-region is written from one (heuristic) XCD; (3) gather goes 8 groups
// of 8 lanes with uint4 row loads (8 edge streams at degree~13).

#define NUM_USERS 100000
#define NUM_ITEMS 50000
#define EMB_DIM   64
#define N_EDGES   2000000
#define N_NODES   (NUM_USERS + NUM_ITEMS)          // 150000
#define NODE_FLOATS (N_NODES * EMB_DIM)            // 9,600,000
#define NODE_F4     (NODE_FLOATS / 4)              // 2,400,000

#define NBUCKET  512
#define NPB      293        // nodes per bucket; 512*293 = 150016 >= 150000
#define NPART    8          // reservation partitions (XCD heuristic)
#define NCNT     (NBUCKET * NPART)                  // 4096
#define BT       512        // threads in bucket passes
#define VPT      8          // edges per thread in bucket passes
#define TILE     (BT * VPT)                         // 4096
#define NTILE    ((N_EDGES + TILE - 1) / TILE)      // 489

typedef unsigned int uint;
typedef unsigned short ushort;
typedef unsigned long long u64;

__device__ __forceinline__ uint pack2_bf16(float a, float b) {
    uint ua = __float_as_uint(a), ub = __float_as_uint(b);
    ua += 0x7FFFu + ((ua >> 16) & 1u);      // RNE
    ub += 0x7FFFu + ((ub >> 16) & 1u);
    return (ua >> 16) | (ub & 0xFFFF0000u);
}
__device__ __forceinline__ float bflo(uint u) { return __uint_as_float(u << 16); }
__device__ __forceinline__ float bfhi(uint u) { return __uint_as_float(u & 0xFFFF0000u); }

// ---------- init: egoA(bf16) = concat(user,item) ----------
__global__ void lgcn_init(const float4* __restrict__ user,
                          const float4* __restrict__ item,
                          uint2* __restrict__ egoA) {
    const int n_user4 = NUM_USERS * EMB_DIM / 4;
    for (int i = blockIdx.x * blockDim.x + threadIdx.x; i < NODE_F4;
         i += gridDim.x * blockDim.x) {
        float4 v = (i < n_user4) ? user[i] : item[i - n_user4];
        egoA[i] = make_uint2(pack2_bf16(v.x, v.y), pack2_bf16(v.z, v.w));
    }
}

__global__ void zero_ints(int* __restrict__ p, int n) {
    int i = blockIdx.x * blockDim.x + threadIdx.x;
    if (i < n) p[i] = 0;
}

// ---------- pass A: histogram into (bucket, partition) counters ----------
__global__ __launch_bounds__(BT) void bucket_hist(const int* __restrict__ src,
                                                  int* __restrict__ bucketCount) {
    __shared__ int cnt[NBUCKET];
    int t = threadIdx.x;
    int part = blockIdx.x & (NPART - 1);
    cnt[t] = 0;
    __syncthreads();
    int base = blockIdx.x * TILE + t;
    #pragma unroll
    for (int k = 0; k < VPT; ++k) {
        int e = base + k * BT;
        if (e < N_EDGES) atomicAdd(&cnt[src[e] / NPB], 1);
    }
    __syncthreads();
    int c = cnt[t];
    if (c) atomicAdd(&bucketCount[t * NPART + part], c);
}

// ---------- scan over 4096 (bucket,part) counters (1 block, 1024 thr) ----------
__global__ __launch_bounds__(1024) void bucket_scan(const int* __restrict__ bucketCount,
                                                    int* __restrict__ bucketOffset,
                                                    int* __restrict__ gCur,
                                                    int* __restrict__ rowPtr) {
    __shared__ int s[1024];
    int t = threadIdx.x;
    int4 c = *(const int4*)(bucketCount + t * 4);
    int sum = c.x + c.y + c.z + c.w;
    s[t] = sum;
    __syncthreads();
    for (int off = 1; off < 1024; off <<= 1) {
        int x = (t >= off) ? s[t - off] : 0;
        __syncthreads();
        s[t] += x;
        __syncthreads();
    }
    int base = s[t] - sum;   // exclusive
    int i0 = t * 4;
    bucketOffset[i0]     = base;
    bucketOffset[i0 + 1] = base + c.x;
    bucketOffset[i0 + 2] = base + c.x + c.y;
    bucketOffset[i0 + 3] = base + c.x + c.y + c.z;
    gCur[i0]     = base;
    gCur[i0 + 1] = base + c.x;
    gCur[i0 + 2] = base + c.x + c.y;
    gCur[i0 + 3] = base + c.x + c.y + c.z;
    if (t == 0) {
        bucketOffset[NCNT] = N_EDGES;
        rowPtr[N_NODES] = N_EDGES;
    }
}

// ---------- pass B: scatter packed edges into (bucket,part) runs ----------
// packed u64: [norm:32][src_local:9][dst:18]
__global__ __launch_bounds__(BT) void bucket_scatter(const int* __restrict__ src,
                                                     const int* __restrict__ dst,
                                                     const float* __restrict__ norm,
                                                     int* __restrict__ gCur,
                                                     u64* __restrict__ bpair) {
    __shared__ int cnt[NBUCKET];
    __shared__ int bbase[NBUCKET];
    int t = threadIdx.x;
    int part = blockIdx.x & (NPART - 1);
    cnt[t] = 0;
    __syncthreads();
    int base = blockIdx.x * TILE + t;
    #pragma unroll
    for (int k = 0; k < VPT; ++k) {
        int e = base + k * BT;
        if (e < N_EDGES) atomicAdd(&cnt[src[e] / NPB], 1);
    }
    __syncthreads();
    int c = cnt[t];
    bbase[t] = c ? atomicAdd(&gCur[t * NPART + part], c) : 0;
    __syncthreads();
    cnt[t] = 0;
    __syncthreads();
    #pragma unroll
    for (int k = 0; k < VPT; ++k) {
        int e = base + k * BT;
        if (e < N_EDGES) {
            int s = src[e];
            int b = s / NPB;
            int sl = s - b * NPB;                    // 0..292
            int r = atomicAdd(&cnt[b], 1);
            uint lo = (uint)dst[e] | ((uint)sl << 18);
            u64 packed = (u64)lo | ((u64)(uint)__float_as_uint(norm[e]) << 32);
            bpair[bbase[b] + r] = packed;
        }
    }
}

// ---------- pass C: per-bucket CSR finalize (counting sort by src_local) ----------
__global__ __launch_bounds__(1024) void csr_finalize(const int* __restrict__ bucketOffset,
                                                     const u64* __restrict__ bpair,
                                                     int* __restrict__ rowPtr,
                                                     u64* __restrict__ pairs) {
    __shared__ int cnt[NBUCKET];
    __shared__ int cur[NBUCKET];
    int b = blockIdx.x;
    int t = threadIdx.x;          // 1024 threads
    int beg = bucketOffset[b * NPART];
    int end = bucketOffset[b * NPART + NPART];
    int nodeBase = b * NPB;

    if (t < NBUCKET) cnt[t] = 0;
    __syncthreads();
    for (int i = beg + t; i < end; i += 1024) {
        uint lo = (uint)bpair[i];
        atomicAdd(&cnt[(lo >> 18) & 0x1FF], 1);
    }
    __syncthreads();
    int v = (t < NBUCKET) ? cnt[t] : 0;
    for (int off = 1; off < NBUCKET; off <<= 1) {     // inclusive scan, 512-wide
        int x = (t >= off && t < NBUCKET) ? cnt[t - off] : 0;
        __syncthreads();
        if (t < NBUCKET) cnt[t] += x;
        __syncthreads();
    }
    if (t < NBUCKET) {
        int excl = cnt[t] - v;
        cur[t] = excl;
        int node = nodeBase + t;
        if (t < NPB && node < N_NODES) rowPtr[node] = beg + excl;
    }
    __syncthreads();
    for (int i = beg + t; i < end; i += 1024) {
        u64 p = bpair[i];
        int s = ((uint)p >> 18) & 0x1FF;
        int r = atomicAdd(&cur[s], 1);
        pairs[beg + r] = p;
    }
}

// ---------- gather: 1 node/wave, 8 lane-groups of 8, uint4 row loads ----------
__global__ void lgcn_gather(const ushort* __restrict__ ego,
                            ushort* __restrict__ nego,
                            float* __restrict__ acc,
                            const ushort* __restrict__ ego0,
                            const int* __restrict__ rowPtr,
                            const u64* __restrict__ pairs,
                            float scale, int writeEgo, int accFromEgo0) {
    int node = blockIdx.x * 4 + (threadIdx.x >> 6);
    int lane = threadIdx.x & 63;
    int g    = lane >> 3;           // 8 edge streams
    int sub  = lane & 7;            // 8 bf16 per lane
    if (node >= N_NODES) return;
    int beg = rowPtr[node];
    int end = rowPtr[node + 1];

    float s0 = 0.f, s1 = 0.f, s2 = 0.f, s3 = 0.f;
    float s4 = 0.f, s5 = 0.f, s6 = 0.f, s7 = 0.f;
    for (int i = beg + g; i < end; i += 8) {
        u64 p = __builtin_nontemporal_load(&pairs[i]);
        uint lo = (uint)p;
        float w = __uint_as_float((uint)(p >> 32));
        int d = lo & 0x3FFFF;
        uint4 r = *(const uint4*)(ego + ((size_t)d << 6) + (sub << 3));
        s0 += w * bflo(r.x);  s1 += w * bfhi(r.x);
        s2 += w * bflo(r.y);  s3 += w * bfhi(r.y);
        s4 += w * bflo(r.z);  s5 += w * bfhi(r.z);
        s6 += w * bflo(r.w);  s7 += w * bfhi(r.w);
    }

    // reduce 8 groups -> lanes 0-7
    s0 += __shfl_down(s0, 32); s1 += __shfl_down(s1, 32);
    s2 += __shfl_down(s2, 32); s3 += __shfl_down(s3, 32);
    s4 += __shfl_down(s4, 32); s5 += __shfl_down(s5, 32);
    s6 += __shfl_down(s6, 32); s7 += __shfl_down(s7, 32);
    s0 += __shfl_down(s0, 16); s1 += __shfl_down(s1, 16);
    s2 += __shfl_down(s2, 16); s3 += __shfl_down(s3, 16);
    s4 += __shfl_down(s4, 16); s5 += __shfl_down(s5, 16);
    s6 += __shfl_down(s6, 16); s7 += __shfl_down(s7, 16);
    s0 += __shfl_down(s0, 8);  s1 += __shfl_down(s1, 8);
    s2 += __shfl_down(s2, 8);  s3 += __shfl_down(s3, 8);
    s4 += __shfl_down(s4, 8);  s5 += __shfl_down(s5, 8);
    s6 += __shfl_down(s6, 8);  s7 += __shfl_down(s7, 8);

    if (lane < 8) {
        size_t ro = ((size_t)node << 6) + (lane << 3);   // dims lane*8..lane*8+7
        float4* ap = (float4*)(acc + ro);
        float4 a0, a1;
        if (accFromEgo0) {
            uint4 z = *(const uint4*)(ego0 + ro);
            a0 = make_float4(bflo(z.x), bfhi(z.x), bflo(z.y), bfhi(z.y));
            a1 = make_float4(bflo(z.z), bfhi(z.z), bflo(z.w), bfhi(z.w));
        } else {
            a0 = ap[0];
            a1 = ap[1];
        }
        a0.x = (a0.x + s0) * scale;
        a0.y = (a0.y + s1) * scale;
        a0.z = (a0.z + s2) * scale;
        a0.w = (a0.w + s3) * scale;
        a1.x = (a1.x + s4) * scale;
        a1.y = (a1.y + s5) * scale;
        a1.z = (a1.z + s6) * scale;
        a1.w = (a1.w + s7) * scale;
        ap[0] = a0;
        ap[1] = a1;
        if (writeEgo) {
            uint4* np = (uint4*)(nego + ro);
            *np = make_uint4(pack2_bf16(s0, s1), pack2_bf16(s2, s3),
                             pack2_bf16(s4, s5), pack2_bf16(s6, s7));
        }
    }
}

extern "C" void kernel_launch(void* const* d_in, const int* in_sizes, int n_in,
                              void* d_out, int out_size, void* d_ws, size_t ws_size,
                              hipStream_t stream) {
    const float* user_emb  = (const float*)d_in[0];
    const float* item_emb  = (const float*)d_in[1];
    const float* edge_norm = (const float*)d_in[2];
    const int*   edge_src  = (const int*)d_in[3];
    const int*   edge_dst  = (const int*)d_in[4];
    float* acc = (float*)d_out;

    char* w = (char*)d_ws;
    ushort* egoA  = (ushort*)w;                      w += (size_t)NODE_FLOATS * 2;   // 19.2 MB
    ushort* egoB  = (ushort*)w;                      w += (size_t)NODE_FLOATS * 2;   // 19.2 MB
    u64*   pairs  = (u64*)w;                         w += (size_t)N_EDGES * 8;       // 16 MB
    u64*   bpair  = (u64*)w;                         w += (size_t)N_EDGES * 8;       // 16 MB
    int*   rowPtr = (int*)w;                         w += (size_t)(N_NODES + 4) * 4;
    int*   bucketCount  = (int*)w;                   w += (size_t)NCNT * 4;
    int*   bucketOffset = (int*)w;                   w += (size_t)(NCNT + 4) * 4;
    int*   gCur   = (int*)w;

    const int T = 256;
    const int EW_BLOCKS = 2048;
    const int GATHER_BLOCKS = (N_NODES + 3) / 4;     // 37500

    lgcn_init<<<EW_BLOCKS, T, 0, stream>>>(
        (const float4*)user_emb, (const float4*)item_emb, (uint2*)egoA);

    zero_ints<<<NCNT / T, T, 0, stream>>>(bucketCount, NCNT);
    bucket_hist<<<NTILE, BT, 0, stream>>>(edge_src, bucketCount);
    bucket_scan<<<1, 1024, 0, stream>>>(bucketCount, bucketOffset, gCur, rowPtr);
    bucket_scatter<<<NTILE, BT, 0, stream>>>(edge_src, edge_dst, edge_norm,
                                             gCur, bpair);
    csr_finalize<<<NBUCKET, 1024, 0, stream>>>(bucketOffset, bpair,
                                               rowPtr, pairs);

    // Layer 1: A -> B, acc = ego0 + B
    lgcn_gather<<<GATHER_BLOCKS, T, 0, stream>>>(egoA, egoB, acc, egoA,
                                                 rowPtr, pairs, 1.0f, 1, 1);
    // Layer 2: B -> A, acc += A
    lgcn_gather<<<GATHER_BLOCKS, T, 0, stream>>>(egoB, egoA, acc, egoA,
                                                 rowPtr, pairs, 1.0f, 1, 0);
    // Layer 3: A -> (none), acc = (acc + ego3) * 0.25
    lgcn_gather<<<GATHER_BLOCKS, T, 0, stream>>>(egoA, egoB, acc, egoA,
                                                 rowPtr, pairs, 0.25f, 0, 0);
}